// Round 4
// baseline (207.092 us; speedup 1.0000x reference)
//
#include <hip/hip_runtime.h>

// SSIM v16: v14 math (bit-exact pk_rhu path, zero-shuffle vstep, BY=256)
// with the march restructured into a 3-slot, fully-unrolled software
// pipeline. Evidence (R0-R2): kernel runs at 1.73 TB/s = latency-limited
// memory delivery (96MB/56us); only ~3 loads/wave in flight because the
// old ping-pong had ~1 chunk-time of load->use cover. New march: preload
// chunks 0..2, issue hload(c+2) at the top of step c -> 2 chunk-times of
// cover, 8 loads/wave in flight (~6KB/CU), model ~4.1 TB/s.
// v15's hand-written v_cvt_pk_bf16_f32 produced NaN -> reverted to the
// proven pk_rhu (absmax must be exactly 0.0078125, bit-identical to v14).
//
// Layout identity (unchanged): V-MFMA B-frag k=lg*8+j, n=ln vs H D-frag
// row=lg*4+j, col=ln. B-row permutation k=lg*8+j <-> window row
// (j<4 ? lg*4+j : 12+lg*4+j) makes lane-local {Dp.x,Dp.y,Dc.x,Dc.y} the
// B-frag verbatim; permutation absorbed into whv: whv[k][n]=wt[wr(k)-n-3].

typedef __attribute__((ext_vector_type(8))) short bf16x8;
typedef __attribute__((ext_vector_type(4))) float f32x4;

constexpr int PAD  = 5;
constexpr int TX   = 64;             // block out-cols (4 waves x 16)
constexpr int BY   = 256;            // block out-rows
constexpr int IMW  = 512;
constexpr int IMH  = 512;
constexpr int NPL  = 48;
constexpr int GX   = IMW / TX;       // 8
constexpr int GYB  = IMH / BY;       // 2
constexpr int NBLK = GX * GYB * NPL; // 768
constexpr int NCH  = BY / 16;        // 16 processed-chunk steps (chunks 0..16)
constexpr float C1c = 0.01f * 0.01f;
constexpr float C2c = 0.03f * 0.03f;

union frag {
    bf16x8 f;
    unsigned int u[4];
    uint4 q;
};

// RNE f32->bf16 pair pack (setup kernel only).
__device__ __forceinline__ unsigned int pk_bf16(float lo, float hi) {
    unsigned int a = __float_as_uint(lo);
    unsigned int b = __float_as_uint(hi);
    a += 0x7FFFu + ((a >> 16) & 1u);
    b += 0x7FFFu + ((b >> 16) & 1u);
    return (b & 0xFFFF0000u) | (a >> 16);
}

// Fast pack: round-half-up + byte-perm merge (3 VALU ops per pair).
__device__ __forceinline__ unsigned int pk_rhu(float lo, float hi, unsigned sel) {
    unsigned int a = __float_as_uint(lo) + 0x8000u;
    unsigned int b = __float_as_uint(hi) + 0x8000u;
    unsigned int r;
    asm("v_perm_b32 %0, %1, %2, %3" : "=v"(r) : "v"(b), "v"(a), "s"(sel));
    return r;
}

// Normalized 11-tap Gaussian (sigma=1.5); wt[d] for d in [0,11), else 0.
__device__ __forceinline__ float wsel(int d) {
    float w = 0.f;
    w = (d == 0 || d == 10) ? 0.00102838f : w;
    w = (d == 1 || d == 9)  ? 0.00759876f : w;
    w = (d == 2 || d == 8)  ? 0.03600077f : w;
    w = (d == 3 || d == 7)  ? 0.10936082f : w;
    w = (d == 4 || d == 6)  ? 0.21300553f : w;
    w = (d == 5)            ? 0.26601171f : w;
    return w;
}

// Per-lane weight fragments (8 words/lane):
//   words 0..3: whf  — H-pass B-frag,  W[k][n] = wt[k-n-3],   k = lg*8+j
//   words 4..7: whv  — V-pass A-frag with permuted rows,
//                      W'[k][n] = wt[wr(k)-n-3],
//                      wr(k) = (j<4 ? lg*4+j : 12+lg*4+j), j = k&7
__global__ void ssim_weight_setup(unsigned int* __restrict__ wbuf)
{
    const int lane = threadIdx.x & 63;
    const int ln   = lane & 15;
    const int lg   = lane >> 4;
#pragma unroll
    for (int w = 0; w < 4; ++w) {
        const int ka = lg * 8 + 2 * w;
        wbuf[lane * 8 + w] = pk_bf16(wsel(ka - ln - 3), wsel(ka + 1 - ln - 3));
        const int j0  = 2 * w;
        const int wr0 = (j0 < 4) ? (lg * 4 + j0) : (12 + lg * 4 + j0);
        wbuf[lane * 8 + 4 + w] = pk_bf16(wsel(wr0 - ln - 3), wsel(wr0 + 1 - ln - 3));
    }
}

__global__ __launch_bounds__(256, 4)
void ssim_mfma(const float* __restrict__ img1, const float* __restrict__ img2,
               const unsigned int* __restrict__ wbuf,
               float* __restrict__ partials)
{
    const int tid  = threadIdx.x;
    const int lane = tid & 63;
    const int wave = tid >> 6;        // 0..3
    const int ln   = lane & 15;
    const int lg   = lane >> 4;       // 0..3
    const int tx0w = blockIdx.x * TX + wave * 16;   // wave's 16 out-cols
    const int y0   = blockIdx.y * BY;
    const float* __restrict__ p1 = img1 + (size_t)blockIdx.z * (IMW * IMH);
    const float* __restrict__ p2 = img2 + (size_t)blockIdx.z * (IMW * IMH);
    const unsigned int sel = 0x07060302u;

    frag whf, whv;
    whf.q = reinterpret_cast<const uint4*>(wbuf)[lane * 2];
    whv.q = reinterpret_cast<const uint4*>(wbuf)[lane * 2 + 1];

    const f32x4 z = {0.f, 0.f, 0.f, 0.f};
    const int cbase = tx0w - 8 + lg * 8;            // lane's first img col

    // Load chunk c: 16 h-rows (img rows y0+16c-8 .. +7), 32 cols window.
    auto hload = [&](int c, float* a, float* b) {
        const int irow = y0 + 16 * c - 8 + ln;
        const bool rowok = (unsigned)irow < (unsigned)IMH;
#pragma unroll
        for (int h = 0; h < 2; ++h) {
            const int c4 = cbase + 4 * h;
            float4 va = make_float4(0.f, 0.f, 0.f, 0.f);
            float4 vb = make_float4(0.f, 0.f, 0.f, 0.f);
            if (rowok && ((unsigned)c4 <= (unsigned)(IMW - 4))) {
                va = *reinterpret_cast<const float4*>(p1 + (size_t)irow * IMW + c4);
                vb = *reinterpret_cast<const float4*>(p2 + (size_t)irow * IMW + c4);
            }
            a[4*h+0] = va.x; a[4*h+1] = va.y; a[4*h+2] = va.z; a[4*h+3] = va.w;
            b[4*h+0] = vb.x; b[4*h+1] = vb.y; b[4*h+2] = vb.z; b[4*h+3] = vb.w;
        }
    };

    // H-pass for one chunk: 5 MFMAs -> packed D (uint2 per plane).
    auto hproc = [&](const float* a, const float* b, uint2* D) {
        frag fa, fb, faa, fbb, fab;
#pragma unroll
        for (int w = 0; w < 4; ++w) {
            const float a0 = a[2*w], a1 = a[2*w+1];
            const float b0 = b[2*w], b1 = b[2*w+1];
            fa.u[w]  = pk_rhu(a0,      a1,      sel);
            fb.u[w]  = pk_rhu(b0,      b1,      sel);
            faa.u[w] = pk_rhu(a0 * a0, a1 * a1, sel);
            fbb.u[w] = pk_rhu(b0 * b0, b1 * b1, sel);
            fab.u[w] = pk_rhu(a0 * b0, a1 * b1, sel);
        }
        f32x4 d;
        d = __builtin_amdgcn_mfma_f32_16x16x32_bf16(fa.f,  whf.f, z, 0, 0, 0);
        D[0] = make_uint2(pk_rhu(d[0], d[1], sel), pk_rhu(d[2], d[3], sel));
        d = __builtin_amdgcn_mfma_f32_16x16x32_bf16(fb.f,  whf.f, z, 0, 0, 0);
        D[1] = make_uint2(pk_rhu(d[0], d[1], sel), pk_rhu(d[2], d[3], sel));
        d = __builtin_amdgcn_mfma_f32_16x16x32_bf16(faa.f, whf.f, z, 0, 0, 0);
        D[2] = make_uint2(pk_rhu(d[0], d[1], sel), pk_rhu(d[2], d[3], sel));
        d = __builtin_amdgcn_mfma_f32_16x16x32_bf16(fbb.f, whf.f, z, 0, 0, 0);
        D[3] = make_uint2(pk_rhu(d[0], d[1], sel), pk_rhu(d[2], d[3], sel));
        d = __builtin_amdgcn_mfma_f32_16x16x32_bf16(fab.f, whf.f, z, 0, 0, 0);
        D[4] = make_uint2(pk_rhu(d[0], d[1], sel), pk_rhu(d[2], d[3], sel));
    };

    float lsum = 0.f;

    // V-pass for one 16-row out-tile from D_prev (chunk t) + D_cur (chunk t+1).
    auto vstep = [&](const uint2* Dp, const uint2* Dc) {
        f32x4 res[5];
#pragma unroll
        for (int p = 0; p < 5; ++p) {
            frag Bf;
            Bf.u[0] = Dp[p].x; Bf.u[1] = Dp[p].y;
            Bf.u[2] = Dc[p].x; Bf.u[3] = Dc[p].y;
            res[p] = __builtin_amdgcn_mfma_f32_16x16x32_bf16(whv.f, Bf.f, z, 0, 0, 0);
        }
#pragma unroll
        for (int j = 0; j < 4; ++j) {
            const float mu1 = res[0][j];
            const float mu2 = res[1][j];
            const float m1s = mu1 * mu1;
            const float m2s = mu2 * mu2;
            const float m12 = mu1 * mu2;
            const float s11 = res[2][j] - m1s;
            const float s22 = res[3][j] - m2s;
            const float s12 = res[4][j] - m12;
            const float num = (2.f * m12 + C1c) * (2.f * s12 + C2c);
            const float den = (m1s + m2s + C1c) * (s11 + s22 + C2c);
            lsum = fmaf(num, __builtin_amdgcn_rcpf(den), lsum);
        }
    };

    // ---- Main march: 3-slot rotation, fully unrolled, 2-chunk lookahead ----
    // Slots s0,s1,s2 hold chunks c with c%3 == 0,1,2. Preload 0,1,2; at step
    // c issue hload(c+2) into slot (c+2)%3 == (c-1)%3 (freed at step c-1).
    float sa0[8], sb0[8], sa1[8], sb1[8], sa2[8], sb2[8];
    uint2 DA[5], DB[5];

    hload(0, sa0, sb0);
    hload(1, sa1, sb1);
    hload(2, sa2, sb2);
    hproc(sa0, sb0, DA);                  // D of chunk 0

#pragma unroll
    for (int c = 1; c <= NCH; ++c) {      // process chunk c, emit tile c-1
        float* la = ((c + 2) % 3 == 0) ? sa0 : ((c + 2) % 3 == 1) ? sa1 : sa2;
        float* lb = ((c + 2) % 3 == 0) ? sb0 : ((c + 2) % 3 == 1) ? sb1 : sb2;
        if (c + 2 <= NCH) hload(c + 2, la, lb);       // chunks 3..16

        float* pa = (c % 3 == 0) ? sa0 : (c % 3 == 1) ? sa1 : sa2;
        float* pb = (c % 3 == 0) ? sb0 : (c % 3 == 1) ? sb1 : sb2;
        uint2* Dp = (c & 1) ? DA : DB;
        uint2* Dc = (c & 1) ? DB : DA;
        hproc(pa, pb, Dc);                // D of chunk c
        vstep(Dp, Dc);                    // tile c-1
    }

    // ---- Block reduction -> per-block partial ----
#pragma unroll
    for (int off = 32; off > 0; off >>= 1)
        lsum += __shfl_down(lsum, off, 64);

    __shared__ float wsum[4];
    if (lane == 0) wsum[wave] = lsum;
    __syncthreads();
    if (tid == 0) {
        float tot = wsum[0] + wsum[1] + wsum[2] + wsum[3];
        const int bid = (blockIdx.z * gridDim.y + blockIdx.y) * gridDim.x + blockIdx.x;
        partials[bid] = tot;
    }
}

__global__ __launch_bounds__(256)
void ssim_reduce_kernel(const float* __restrict__ partials,
                        float* __restrict__ out)
{
    __shared__ double sm[256];
    double s = 0.0;
    for (int i = threadIdx.x; i < NBLK; i += 256) s += (double)partials[i];
    sm[threadIdx.x] = s;
    __syncthreads();
    for (int stride = 128; stride > 0; stride >>= 1) {
        if (threadIdx.x < stride) sm[threadIdx.x] += sm[threadIdx.x + stride];
        __syncthreads();
    }
    if (threadIdx.x == 0) {
        double mean = sm[0] / (double)((size_t)NPL * IMW * IMH);
        out[0] = (float)(1.0 - mean);
    }
}

extern "C" void kernel_launch(void* const* d_in, const int* in_sizes, int n_in,
                              void* d_out, int out_size, void* d_ws, size_t ws_size,
                              hipStream_t stream)
{
    (void)in_sizes; (void)n_in; (void)out_size; (void)ws_size;
    const float* img1 = (const float*)d_in[0];
    const float* img2 = (const float*)d_in[1];
    float* out = (float*)d_out;

    unsigned int* wbuf = (unsigned int*)d_ws;              // 2 KB weight table
    float* partials = (float*)((char*)d_ws + 4096);        // NBLK floats

    ssim_weight_setup<<<1, 64, 0, stream>>>(wbuf);
    dim3 grid(GX, GYB, NPL);
    ssim_mfma<<<grid, 256, 0, stream>>>(img1, img2, wbuf, partials);
    ssim_reduce_kernel<<<1, 256, 0, stream>>>(partials, out);
}

// Round 5
// 132.016 us; speedup vs baseline: 1.5687x; 1.5687x over previous
//
#include <hip/hip_runtime.h>

// SSIM v17: v14 math (bit-exact pk_rhu, zero-shuffle vstep, BY=256) with a
// 4-slot, 3-chunk-lookahead software pipeline. v16's pointer-ternary slot
// selection forced the staging arrays into SCRATCH (WRITE_SIZE 24KB->334MB,
// dur 207us) -- rule #20. v17 gets the same deepened pipeline with all 16
// steps explicitly unrolled via a macro whose operands are STATIC array
// names at every call site (v14's proven SROA-safe pattern).
// Theory under test (R3): kernel runs at latency-limited delivery
// (96MB / 1.73TB/s = 56us) because the old march had ~1 chunk-step of
// load->use cover; 3-step cover triples in-flight bytes.
//
// Layout identity (unchanged): V-MFMA B-frag k=lg*8+j, n=ln vs H D-frag
// row=lg*4+j, col=ln. B-row permutation k=lg*8+j <-> window row
// (j<4 ? lg*4+j : 12+lg*4+j) makes lane-local {Dp.x,Dp.y,Dc.x,Dc.y} the
// B-frag verbatim; permutation absorbed into whv: whv[k][n]=wt[wr(k)-n-3].

typedef __attribute__((ext_vector_type(8))) short bf16x8;
typedef __attribute__((ext_vector_type(4))) float f32x4;

constexpr int PAD  = 5;
constexpr int TX   = 64;             // block out-cols (4 waves x 16)
constexpr int BY   = 256;            // block out-rows
constexpr int IMW  = 512;
constexpr int IMH  = 512;
constexpr int NPL  = 48;
constexpr int GX   = IMW / TX;       // 8
constexpr int GYB  = IMH / BY;       // 2
constexpr int NBLK = GX * GYB * NPL; // 768
constexpr int NCH  = BY / 16;        // 16 chunk steps (chunks 0..16)
constexpr float C1c = 0.01f * 0.01f;
constexpr float C2c = 0.03f * 0.03f;

union frag {
    bf16x8 f;
    unsigned int u[4];
    uint4 q;
};

// RNE f32->bf16 pair pack (setup kernel only).
__device__ __forceinline__ unsigned int pk_bf16(float lo, float hi) {
    unsigned int a = __float_as_uint(lo);
    unsigned int b = __float_as_uint(hi);
    a += 0x7FFFu + ((a >> 16) & 1u);
    b += 0x7FFFu + ((b >> 16) & 1u);
    return (b & 0xFFFF0000u) | (a >> 16);
}

// Fast pack: round-half-up + byte-perm merge (3 VALU ops per pair).
__device__ __forceinline__ unsigned int pk_rhu(float lo, float hi, unsigned sel) {
    unsigned int a = __float_as_uint(lo) + 0x8000u;
    unsigned int b = __float_as_uint(hi) + 0x8000u;
    unsigned int r;
    asm("v_perm_b32 %0, %1, %2, %3" : "=v"(r) : "v"(b), "v"(a), "s"(sel));
    return r;
}

// Normalized 11-tap Gaussian (sigma=1.5); wt[d] for d in [0,11), else 0.
__device__ __forceinline__ float wsel(int d) {
    float w = 0.f;
    w = (d == 0 || d == 10) ? 0.00102838f : w;
    w = (d == 1 || d == 9)  ? 0.00759876f : w;
    w = (d == 2 || d == 8)  ? 0.03600077f : w;
    w = (d == 3 || d == 7)  ? 0.10936082f : w;
    w = (d == 4 || d == 6)  ? 0.21300553f : w;
    w = (d == 5)            ? 0.26601171f : w;
    return w;
}

// Per-lane weight fragments (8 words/lane):
//   words 0..3: whf  — H-pass B-frag,  W[k][n] = wt[k-n-3],   k = lg*8+j
//   words 4..7: whv  — V-pass A-frag with permuted rows,
//                      W'[k][n] = wt[wr(k)-n-3],
//                      wr(k) = (j<4 ? lg*4+j : 12+lg*4+j), j = k&7
__global__ void ssim_weight_setup(unsigned int* __restrict__ wbuf)
{
    const int lane = threadIdx.x & 63;
    const int ln   = lane & 15;
    const int lg   = lane >> 4;
#pragma unroll
    for (int w = 0; w < 4; ++w) {
        const int ka = lg * 8 + 2 * w;
        wbuf[lane * 8 + w] = pk_bf16(wsel(ka - ln - 3), wsel(ka + 1 - ln - 3));
        const int j0  = 2 * w;
        const int wr0 = (j0 < 4) ? (lg * 4 + j0) : (12 + lg * 4 + j0);
        wbuf[lane * 8 + 4 + w] = pk_bf16(wsel(wr0 - ln - 3), wsel(wr0 + 1 - ln - 3));
    }
}

__global__ __launch_bounds__(256, 4)
void ssim_mfma(const float* __restrict__ img1, const float* __restrict__ img2,
               const unsigned int* __restrict__ wbuf,
               float* __restrict__ partials)
{
    const int tid  = threadIdx.x;
    const int lane = tid & 63;
    const int wave = tid >> 6;        // 0..3
    const int ln   = lane & 15;
    const int lg   = lane >> 4;       // 0..3
    const int tx0w = blockIdx.x * TX + wave * 16;   // wave's 16 out-cols
    const int y0   = blockIdx.y * BY;
    const float* __restrict__ p1 = img1 + (size_t)blockIdx.z * (IMW * IMH);
    const float* __restrict__ p2 = img2 + (size_t)blockIdx.z * (IMW * IMH);
    const unsigned int sel = 0x07060302u;

    frag whf, whv;
    whf.q = reinterpret_cast<const uint4*>(wbuf)[lane * 2];
    whv.q = reinterpret_cast<const uint4*>(wbuf)[lane * 2 + 1];

    const f32x4 z = {0.f, 0.f, 0.f, 0.f};
    const int cbase = tx0w - 8 + lg * 8;            // lane's first img col

    // Load chunk c: 16 h-rows (img rows y0+16c-8 .. +7), 32 cols window.
    auto hload = [&](int c, float* a, float* b) {
        const int irow = y0 + 16 * c - 8 + ln;
        const bool rowok = (unsigned)irow < (unsigned)IMH;
#pragma unroll
        for (int h = 0; h < 2; ++h) {
            const int c4 = cbase + 4 * h;
            float4 va = make_float4(0.f, 0.f, 0.f, 0.f);
            float4 vb = make_float4(0.f, 0.f, 0.f, 0.f);
            if (rowok && ((unsigned)c4 <= (unsigned)(IMW - 4))) {
                va = *reinterpret_cast<const float4*>(p1 + (size_t)irow * IMW + c4);
                vb = *reinterpret_cast<const float4*>(p2 + (size_t)irow * IMW + c4);
            }
            a[4*h+0] = va.x; a[4*h+1] = va.y; a[4*h+2] = va.z; a[4*h+3] = va.w;
            b[4*h+0] = vb.x; b[4*h+1] = vb.y; b[4*h+2] = vb.z; b[4*h+3] = vb.w;
        }
    };

    // H-pass for one chunk: 5 MFMAs -> packed D (uint2 per plane).
    auto hproc = [&](const float* a, const float* b, uint2* D) {
        frag fa, fb, faa, fbb, fab;
#pragma unroll
        for (int w = 0; w < 4; ++w) {
            const float a0 = a[2*w], a1 = a[2*w+1];
            const float b0 = b[2*w], b1 = b[2*w+1];
            fa.u[w]  = pk_rhu(a0,      a1,      sel);
            fb.u[w]  = pk_rhu(b0,      b1,      sel);
            faa.u[w] = pk_rhu(a0 * a0, a1 * a1, sel);
            fbb.u[w] = pk_rhu(b0 * b0, b1 * b1, sel);
            fab.u[w] = pk_rhu(a0 * b0, a1 * b1, sel);
        }
        f32x4 d;
        d = __builtin_amdgcn_mfma_f32_16x16x32_bf16(fa.f,  whf.f, z, 0, 0, 0);
        D[0] = make_uint2(pk_rhu(d[0], d[1], sel), pk_rhu(d[2], d[3], sel));
        d = __builtin_amdgcn_mfma_f32_16x16x32_bf16(fb.f,  whf.f, z, 0, 0, 0);
        D[1] = make_uint2(pk_rhu(d[0], d[1], sel), pk_rhu(d[2], d[3], sel));
        d = __builtin_amdgcn_mfma_f32_16x16x32_bf16(faa.f, whf.f, z, 0, 0, 0);
        D[2] = make_uint2(pk_rhu(d[0], d[1], sel), pk_rhu(d[2], d[3], sel));
        d = __builtin_amdgcn_mfma_f32_16x16x32_bf16(fbb.f, whf.f, z, 0, 0, 0);
        D[3] = make_uint2(pk_rhu(d[0], d[1], sel), pk_rhu(d[2], d[3], sel));
        d = __builtin_amdgcn_mfma_f32_16x16x32_bf16(fab.f, whf.f, z, 0, 0, 0);
        D[4] = make_uint2(pk_rhu(d[0], d[1], sel), pk_rhu(d[2], d[3], sel));
    };

    float lsum = 0.f;

    // V-pass for one 16-row out-tile from D_prev (chunk t) + D_cur (chunk t+1).
    auto vstep = [&](const uint2* Dp, const uint2* Dc) {
        f32x4 res[5];
#pragma unroll
        for (int p = 0; p < 5; ++p) {
            frag Bf;
            Bf.u[0] = Dp[p].x; Bf.u[1] = Dp[p].y;
            Bf.u[2] = Dc[p].x; Bf.u[3] = Dc[p].y;
            res[p] = __builtin_amdgcn_mfma_f32_16x16x32_bf16(whv.f, Bf.f, z, 0, 0, 0);
        }
#pragma unroll
        for (int j = 0; j < 4; ++j) {
            const float mu1 = res[0][j];
            const float mu2 = res[1][j];
            const float m1s = mu1 * mu1;
            const float m2s = mu2 * mu2;
            const float m12 = mu1 * mu2;
            const float s11 = res[2][j] - m1s;
            const float s22 = res[3][j] - m2s;
            const float s12 = res[4][j] - m12;
            const float num = (2.f * m12 + C1c) * (2.f * s12 + C2c);
            const float den = (m1s + m2s + C1c) * (s11 + s22 + C2c);
            lsum = fmaf(num, __builtin_amdgcn_rcpf(den), lsum);
        }
    };

    // ---- Main march: 4-slot rotation, explicit 16-step unroll ----
    // Slot k holds chunk c with c%4==k. Preload chunks 0..3. Step c:
    // issue hload(c+3) into slot (c-1)%4 (freed last step), process slot
    // c%4 (loaded 3 steps ago), emit tile c-1. All operands are STATIC
    // array names -> SROA keeps everything in registers (no v16 scratch).
    float a0s[8], b0s[8], a1s[8], b1s[8], a2s[8], b2s[8], a3s[8], b3s[8];
    uint2 DA[5], DB[5];

    hload(0, a0s, b0s);
    hload(1, a1s, b1s);
    hload(2, a2s, b2s);
    hload(3, a3s, b3s);
    hproc(a0s, b0s, DA);                  // D of chunk 0

#define STEP(c, PA, PB, LA, LB, DP, DC)            \
    do {                                           \
        if ((c) + 3 <= NCH) hload((c) + 3, LA, LB);\
        hproc(PA, PB, DC);                         \
        vstep(DP, DC);                             \
    } while (0)

    STEP( 1, a1s, b1s, a0s, b0s, DA, DB);   // load chunk 4
    STEP( 2, a2s, b2s, a1s, b1s, DB, DA);   // load chunk 5
    STEP( 3, a3s, b3s, a2s, b2s, DA, DB);   // load chunk 6
    STEP( 4, a0s, b0s, a3s, b3s, DB, DA);   // load chunk 7
    STEP( 5, a1s, b1s, a0s, b0s, DA, DB);   // load chunk 8
    STEP( 6, a2s, b2s, a1s, b1s, DB, DA);   // load chunk 9
    STEP( 7, a3s, b3s, a2s, b2s, DA, DB);   // load chunk 10
    STEP( 8, a0s, b0s, a3s, b3s, DB, DA);   // load chunk 11
    STEP( 9, a1s, b1s, a0s, b0s, DA, DB);   // load chunk 12
    STEP(10, a2s, b2s, a1s, b1s, DB, DA);   // load chunk 13
    STEP(11, a3s, b3s, a2s, b2s, DA, DB);   // load chunk 14
    STEP(12, a0s, b0s, a3s, b3s, DB, DA);   // load chunk 15
    STEP(13, a1s, b1s, a0s, b0s, DA, DB);   // load chunk 16
    STEP(14, a2s, b2s, a1s, b1s, DB, DA);   // no load
    STEP(15, a3s, b3s, a2s, b2s, DA, DB);   // no load
    STEP(16, a0s, b0s, a3s, b3s, DB, DA);   // no load
#undef STEP

    // ---- Block reduction -> per-block partial ----
#pragma unroll
    for (int off = 32; off > 0; off >>= 1)
        lsum += __shfl_down(lsum, off, 64);

    __shared__ float wsum[4];
    if (lane == 0) wsum[wave] = lsum;
    __syncthreads();
    if (tid == 0) {
        float tot = wsum[0] + wsum[1] + wsum[2] + wsum[3];
        const int bid = (blockIdx.z * gridDim.y + blockIdx.y) * gridDim.x + blockIdx.x;
        partials[bid] = tot;
    }
}

__global__ __launch_bounds__(256)
void ssim_reduce_kernel(const float* __restrict__ partials,
                        float* __restrict__ out)
{
    __shared__ double sm[256];
    double s = 0.0;
    for (int i = threadIdx.x; i < NBLK; i += 256) s += (double)partials[i];
    sm[threadIdx.x] = s;
    __syncthreads();
    for (int stride = 128; stride > 0; stride >>= 1) {
        if (threadIdx.x < stride) sm[threadIdx.x] += sm[threadIdx.x + stride];
        __syncthreads();
    }
    if (threadIdx.x == 0) {
        double mean = sm[0] / (double)((size_t)NPL * IMW * IMH);
        out[0] = (float)(1.0 - mean);
    }
}

extern "C" void kernel_launch(void* const* d_in, const int* in_sizes, int n_in,
                              void* d_out, int out_size, void* d_ws, size_t ws_size,
                              hipStream_t stream)
{
    (void)in_sizes; (void)n_in; (void)out_size; (void)ws_size;
    const float* img1 = (const float*)d_in[0];
    const float* img2 = (const float*)d_in[1];
    float* out = (float*)d_out;

    unsigned int* wbuf = (unsigned int*)d_ws;              // 2 KB weight table
    float* partials = (float*)((char*)d_ws + 4096);        // NBLK floats

    ssim_weight_setup<<<1, 64, 0, stream>>>(wbuf);
    dim3 grid(GX, GYB, NPL);
    ssim_mfma<<<grid, 256, 0, stream>>>(img1, img2, wbuf, partials);
    ssim_reduce_kernel<<<1, 256, 0, stream>>>(partials, out);
}

// Round 6
// 48.786 us; speedup vs baseline: 4.2449x; 2.7060x over previous
//
#include <hip/hip_runtime.h>

// SSIM v18: v14 math (bit-exact pk_rhu, zero-shuffle vstep, BY=256) with a
// 4-slot / 3-chunk-lookahead pipeline, implemented scratch-proof:
//  - v16 failed: pointer-ternary slot select -> allocas escape -> scratch.
//  - v17 failed: 16x macro expansion -> inliner declined the (non-forced)
//    lambdas -> address-taken arrays -> scratch (WRITE_SIZE 187MB).
//  - v18: helpers are __forceinline__ FREE FUNCTIONS (always_inline, no
//    cost model) + rolled loop (4 iters x 4 static-name steps) keeps the
//    pre-unroll body small. launch_bounds(256,3): grid=768 is 3 blocks/CU
//    anyway, so cap VGPR at ~168 instead of 128 -> no pressure spill.
// Theory under test (R3): kernel runs at latency-limited delivery
// (96MB / 1.73TB/s = 56us) because load->use cover was ~1 chunk-step;
// 3-step cover triples in-flight bytes per wave.
//
// Layout identity (unchanged): V-MFMA B-frag k=lg*8+j, n=ln vs H D-frag
// row=lg*4+j, col=ln. B-row permutation k=lg*8+j <-> window row
// (j<4 ? lg*4+j : 12+lg*4+j) makes lane-local {Dp.x,Dp.y,Dc.x,Dc.y} the
// B-frag verbatim; permutation absorbed into whv: whv[k][n]=wt[wr(k)-n-3].

typedef __attribute__((ext_vector_type(8))) short bf16x8;
typedef __attribute__((ext_vector_type(4))) float f32x4;

constexpr int PAD  = 5;
constexpr int TX   = 64;             // block out-cols (4 waves x 16)
constexpr int BY   = 256;            // block out-rows
constexpr int IMW  = 512;
constexpr int IMH  = 512;
constexpr int NPL  = 48;
constexpr int GX   = IMW / TX;       // 8
constexpr int GYB  = IMH / BY;       // 2
constexpr int NBLK = GX * GYB * NPL; // 768
constexpr int NCH  = BY / 16;        // 16 chunk steps (chunks 0..16)
constexpr float C1c = 0.01f * 0.01f;
constexpr float C2c = 0.03f * 0.03f;

union frag {
    bf16x8 f;
    unsigned int u[4];
    uint4 q;
};

// RNE f32->bf16 pair pack (setup kernel only).
__device__ __forceinline__ unsigned int pk_bf16(float lo, float hi) {
    unsigned int a = __float_as_uint(lo);
    unsigned int b = __float_as_uint(hi);
    a += 0x7FFFu + ((a >> 16) & 1u);
    b += 0x7FFFu + ((b >> 16) & 1u);
    return (b & 0xFFFF0000u) | (a >> 16);
}

// Fast pack: round-half-up + byte-perm merge (3 VALU ops per pair).
__device__ __forceinline__ unsigned int pk_rhu(float lo, float hi, unsigned sel) {
    unsigned int a = __float_as_uint(lo) + 0x8000u;
    unsigned int b = __float_as_uint(hi) + 0x8000u;
    unsigned int r;
    asm("v_perm_b32 %0, %1, %2, %3" : "=v"(r) : "v"(b), "v"(a), "s"(sel));
    return r;
}

// Normalized 11-tap Gaussian (sigma=1.5); wt[d] for d in [0,11), else 0.
__device__ __forceinline__ float wsel(int d) {
    float w = 0.f;
    w = (d == 0 || d == 10) ? 0.00102838f : w;
    w = (d == 1 || d == 9)  ? 0.00759876f : w;
    w = (d == 2 || d == 8)  ? 0.03600077f : w;
    w = (d == 3 || d == 7)  ? 0.10936082f : w;
    w = (d == 4 || d == 6)  ? 0.21300553f : w;
    w = (d == 5)            ? 0.26601171f : w;
    return w;
}

// Per-lane weight fragments (8 words/lane):
//   words 0..3: whf  — H-pass B-frag,  W[k][n] = wt[k-n-3],   k = lg*8+j
//   words 4..7: whv  — V-pass A-frag with permuted rows,
//                      W'[k][n] = wt[wr(k)-n-3],
//                      wr(k) = (j<4 ? lg*4+j : 12+lg*4+j), j = k&7
__global__ void ssim_weight_setup(unsigned int* __restrict__ wbuf)
{
    const int lane = threadIdx.x & 63;
    const int ln   = lane & 15;
    const int lg   = lane >> 4;
#pragma unroll
    for (int w = 0; w < 4; ++w) {
        const int ka = lg * 8 + 2 * w;
        wbuf[lane * 8 + w] = pk_bf16(wsel(ka - ln - 3), wsel(ka + 1 - ln - 3));
        const int j0  = 2 * w;
        const int wr0 = (j0 < 4) ? (lg * 4 + j0) : (12 + lg * 4 + j0);
        wbuf[lane * 8 + 4 + w] = pk_bf16(wsel(wr0 - ln - 3), wsel(wr0 + 1 - ln - 3));
    }
}

// ---- forced-inline pipeline stages (free functions: no inliner bailout,
// ---- call sites dissolve -> SROA promotes every staging array) ----

// Load chunk c: 16 h-rows (img rows y0+16c-8 .. +7), 32 cols window.
__device__ __forceinline__ void hload(const float* __restrict__ p1,
                                      const float* __restrict__ p2,
                                      int y0, int ln, int cbase, int c,
                                      float* __restrict__ a,
                                      float* __restrict__ b)
{
    const int irow = y0 + 16 * c - 8 + ln;
    const bool rowok = (unsigned)irow < (unsigned)IMH;
#pragma unroll
    for (int h = 0; h < 2; ++h) {
        const int c4 = cbase + 4 * h;
        float4 va = make_float4(0.f, 0.f, 0.f, 0.f);
        float4 vb = make_float4(0.f, 0.f, 0.f, 0.f);
        if (rowok && ((unsigned)c4 <= (unsigned)(IMW - 4))) {
            va = *reinterpret_cast<const float4*>(p1 + (size_t)irow * IMW + c4);
            vb = *reinterpret_cast<const float4*>(p2 + (size_t)irow * IMW + c4);
        }
        a[4*h+0] = va.x; a[4*h+1] = va.y; a[4*h+2] = va.z; a[4*h+3] = va.w;
        b[4*h+0] = vb.x; b[4*h+1] = vb.y; b[4*h+2] = vb.z; b[4*h+3] = vb.w;
    }
}

// H-pass for one chunk: 5 MFMAs -> packed D (uint2 per plane).
__device__ __forceinline__ void hproc(const frag& whf, unsigned sel,
                                      const float* __restrict__ a,
                                      const float* __restrict__ b,
                                      uint2* __restrict__ D)
{
    const f32x4 z = {0.f, 0.f, 0.f, 0.f};
    frag fa, fb, faa, fbb, fab;
#pragma unroll
    for (int w = 0; w < 4; ++w) {
        const float a0 = a[2*w], a1 = a[2*w+1];
        const float b0 = b[2*w], b1 = b[2*w+1];
        fa.u[w]  = pk_rhu(a0,      a1,      sel);
        fb.u[w]  = pk_rhu(b0,      b1,      sel);
        faa.u[w] = pk_rhu(a0 * a0, a1 * a1, sel);
        fbb.u[w] = pk_rhu(b0 * b0, b1 * b1, sel);
        fab.u[w] = pk_rhu(a0 * b0, a1 * b1, sel);
    }
    f32x4 d;
    d = __builtin_amdgcn_mfma_f32_16x16x32_bf16(fa.f,  whf.f, z, 0, 0, 0);
    D[0] = make_uint2(pk_rhu(d[0], d[1], sel), pk_rhu(d[2], d[3], sel));
    d = __builtin_amdgcn_mfma_f32_16x16x32_bf16(fb.f,  whf.f, z, 0, 0, 0);
    D[1] = make_uint2(pk_rhu(d[0], d[1], sel), pk_rhu(d[2], d[3], sel));
    d = __builtin_amdgcn_mfma_f32_16x16x32_bf16(faa.f, whf.f, z, 0, 0, 0);
    D[2] = make_uint2(pk_rhu(d[0], d[1], sel), pk_rhu(d[2], d[3], sel));
    d = __builtin_amdgcn_mfma_f32_16x16x32_bf16(fbb.f, whf.f, z, 0, 0, 0);
    D[3] = make_uint2(pk_rhu(d[0], d[1], sel), pk_rhu(d[2], d[3], sel));
    d = __builtin_amdgcn_mfma_f32_16x16x32_bf16(fab.f, whf.f, z, 0, 0, 0);
    D[4] = make_uint2(pk_rhu(d[0], d[1], sel), pk_rhu(d[2], d[3], sel));
}

// V-pass for one 16-row out-tile from D_prev (chunk t) + D_cur (chunk t+1).
__device__ __forceinline__ void vstep(const frag& whv,
                                      const uint2* __restrict__ Dp,
                                      const uint2* __restrict__ Dc,
                                      float& lsum)
{
    const f32x4 z = {0.f, 0.f, 0.f, 0.f};
    f32x4 res[5];
#pragma unroll
    for (int p = 0; p < 5; ++p) {
        frag Bf;
        Bf.u[0] = Dp[p].x; Bf.u[1] = Dp[p].y;
        Bf.u[2] = Dc[p].x; Bf.u[3] = Dc[p].y;
        res[p] = __builtin_amdgcn_mfma_f32_16x16x32_bf16(whv.f, Bf.f, z, 0, 0, 0);
    }
#pragma unroll
    for (int j = 0; j < 4; ++j) {
        const float mu1 = res[0][j];
        const float mu2 = res[1][j];
        const float m1s = mu1 * mu1;
        const float m2s = mu2 * mu2;
        const float m12 = mu1 * mu2;
        const float s11 = res[2][j] - m1s;
        const float s22 = res[3][j] - m2s;
        const float s12 = res[4][j] - m12;
        const float num = (2.f * m12 + C1c) * (2.f * s12 + C2c);
        const float den = (m1s + m2s + C1c) * (s11 + s22 + C2c);
        lsum = fmaf(num, __builtin_amdgcn_rcpf(den), lsum);
    }
}

__global__ __launch_bounds__(256, 3)
void ssim_mfma(const float* __restrict__ img1, const float* __restrict__ img2,
               const unsigned int* __restrict__ wbuf,
               float* __restrict__ partials)
{
    const int tid  = threadIdx.x;
    const int lane = tid & 63;
    const int wave = tid >> 6;        // 0..3
    const int ln   = lane & 15;
    const int lg   = lane >> 4;       // 0..3
    const int tx0w = blockIdx.x * TX + wave * 16;   // wave's 16 out-cols
    const int y0   = blockIdx.y * BY;
    const float* __restrict__ p1 = img1 + (size_t)blockIdx.z * (IMW * IMH);
    const float* __restrict__ p2 = img2 + (size_t)blockIdx.z * (IMW * IMH);
    const unsigned int sel = 0x07060302u;

    frag whf, whv;
    whf.q = reinterpret_cast<const uint4*>(wbuf)[lane * 2];
    whv.q = reinterpret_cast<const uint4*>(wbuf)[lane * 2 + 1];

    const int cbase = tx0w - 8 + lg * 8;            // lane's first img col

    float lsum = 0.f;

    // ---- Main march: 4-slot rotation (slot k holds chunk c, c%4==k),
    // 3-chunk lookahead. Step c: load chunk c+3 into slot (c-1)%4 (freed
    // at step c-1), process slot c%4 (loaded 3 steps ago), emit tile c-1.
    // Rolled loop: 4 iterations x 4 static-name steps (period-4 slots x
    // period-2 D ping-pong both align).
    float a0s[8], b0s[8], a1s[8], b1s[8], a2s[8], b2s[8], a3s[8], b3s[8];
    uint2 DA[5], DB[5];

    hload(p1, p2, y0, ln, cbase, 0, a0s, b0s);
    hload(p1, p2, y0, ln, cbase, 1, a1s, b1s);
    hload(p1, p2, y0, ln, cbase, 2, a2s, b2s);
    hload(p1, p2, y0, ln, cbase, 3, a3s, b3s);
    hproc(whf, sel, a0s, b0s, DA);        // D of chunk 0

    for (int u = 0; u < 4; ++u) {
        const int c0 = 4 * u;             // steps c0+1 .. c0+4
        // step c0+1: process slot1, load chunk c0+4 -> slot0
        if (c0 + 4 <= NCH) hload(p1, p2, y0, ln, cbase, c0 + 4, a0s, b0s);
        hproc(whf, sel, a1s, b1s, DB);
        vstep(whv, DA, DB, lsum);
        // step c0+2: process slot2, load chunk c0+5 -> slot1
        if (c0 + 5 <= NCH) hload(p1, p2, y0, ln, cbase, c0 + 5, a1s, b1s);
        hproc(whf, sel, a2s, b2s, DA);
        vstep(whv, DB, DA, lsum);
        // step c0+3: process slot3, load chunk c0+6 -> slot2
        if (c0 + 6 <= NCH) hload(p1, p2, y0, ln, cbase, c0 + 6, a2s, b2s);
        hproc(whf, sel, a3s, b3s, DB);
        vstep(whv, DA, DB, lsum);
        // step c0+4: process slot0, load chunk c0+7 -> slot3
        if (c0 + 7 <= NCH) hload(p1, p2, y0, ln, cbase, c0 + 7, a3s, b3s);
        hproc(whf, sel, a0s, b0s, DA);
        vstep(whv, DB, DA, lsum);
    }

    // ---- Block reduction -> per-block partial ----
#pragma unroll
    for (int off = 32; off > 0; off >>= 1)
        lsum += __shfl_down(lsum, off, 64);

    __shared__ float wsum[4];
    if (lane == 0) wsum[wave] = lsum;
    __syncthreads();
    if (tid == 0) {
        float tot = wsum[0] + wsum[1] + wsum[2] + wsum[3];
        const int bid = (blockIdx.z * gridDim.y + blockIdx.y) * gridDim.x + blockIdx.x;
        partials[bid] = tot;
    }
}

__global__ __launch_bounds__(256)
void ssim_reduce_kernel(const float* __restrict__ partials,
                        float* __restrict__ out)
{
    __shared__ double sm[256];
    double s = 0.0;
    for (int i = threadIdx.x; i < NBLK; i += 256) s += (double)partials[i];
    sm[threadIdx.x] = s;
    __syncthreads();
    for (int stride = 128; stride > 0; stride >>= 1) {
        if (threadIdx.x < stride) sm[threadIdx.x] += sm[threadIdx.x + stride];
        __syncthreads();
    }
    if (threadIdx.x == 0) {
        double mean = sm[0] / (double)((size_t)NPL * IMW * IMH);
        out[0] = (float)(1.0 - mean);
    }
}

extern "C" void kernel_launch(void* const* d_in, const int* in_sizes, int n_in,
                              void* d_out, int out_size, void* d_ws, size_t ws_size,
                              hipStream_t stream)
{
    (void)in_sizes; (void)n_in; (void)out_size; (void)ws_size;
    const float* img1 = (const float*)d_in[0];
    const float* img2 = (const float*)d_in[1];
    float* out = (float*)d_out;

    unsigned int* wbuf = (unsigned int*)d_ws;              // 2 KB weight table
    float* partials = (float*)((char*)d_ws + 4096);        // NBLK floats

    ssim_weight_setup<<<1, 64, 0, stream>>>(wbuf);
    dim3 grid(GX, GYB, NPL);
    ssim_mfma<<<grid, 256, 0, stream>>>(img1, img2, wbuf, partials);
    ssim_reduce_kernel<<<1, 256, 0, stream>>>(partials, out);
}